// Round 7
// baseline (695.274 us; speedup 1.0000x reference)
//
#include <hip/hip_runtime.h>
#include <hip/hip_bf16.h>
#include <math.h>

typedef __hip_bfloat16 bf16;
typedef __attribute__((ext_vector_type(8))) short short8;
typedef __attribute__((ext_vector_type(4))) short s16x4;
typedef __attribute__((ext_vector_type(4))) float f32x4;
typedef __attribute__((ext_vector_type(2))) float f32x2;

#define Bb 8
#define Nn 256
#define Hh 8
#define DEPTHd 4
#define BN 2048
#define RTOT 524288
#define RELB 8192          // RTOT/64 relation blocks
#define JB 32              // BN/64 joint blocks
#define XTS 136

// k_rel3 LDS layout (bytes). Same footprint as round-3 (3 blocks/CU), but Bst is
// now 2 x 8KB wave-private half-strip buffers driven by counted vmcnt (no barriers
// in the K-loops).
#define X_OFF 0            // [64][264] bf16 = 33792
#define BST_OFF 33792      // 2 x 8192 double-buffer = 16384
#define SST_OFF 50176      // [64][4][2] f32 = 2048
#define SSF_OFF 52224      // [64][2] f32 = 512
#define SMEM_TOT 52736     // 3 blocks/CU
#define X2S 264
#define X3S 136

__device__ inline float toF(float v) { return v; }
__device__ inline float toF(bf16 v) { return __bfloat162float(v); }
__device__ inline void stF(float* p, float v) { *p = v; }
__device__ inline void stF(bf16* p, float v) { *p = __float2bfloat16(v); }

__device__ inline void gload16(const bf16* g, bf16* l) {
  __builtin_amdgcn_global_load_lds(
      (const __attribute__((address_space(1))) unsigned int*)g,
      (__attribute__((address_space(3))) unsigned int*)l, 16, 0, 0);
}

// =============== k_rel3: relation encoder, fused 3-layer MLP + LN + 1x1conv ===============
// KEY INSIGHT (round 7): Bst staging is WAVE-PRIVATE (wave wv stages and reads only
// its own col/row slice), so the K-loops need NO barriers at all -- just per-wave
// counted `s_waitcnt vmcnt(N)` with a 2-deep half-strip double buffer in the SAME
// 16KB Bst region (3 blocks/CU preserved; rounds 4/5 showed occupancy loss kills).
// Round-3's 2-barriers-per-strip exposed full staging latency 12x/block (237us);
// here stage(k+2) is issued right after consuming buffer (k&1) and is waited only
// at iteration k+2 -> latency hides under ~1 iteration of MFMAs + 12-wave TLP.
// "memory"-clobbered asm prevents hoisting post-loop loads into the counted window;
// sched_barrier(0) pins stage-issue after MFMA consumption (lgkm waits precede it).
// MFMA operands SWAPPED (D = W_frag * X_frag): lane's 4 acc regs = 4 consecutive
// output cols of one row -> packed b64 LDS writes / f32x4 bias loads.
// Blocks [0,RELB): relation -> attnR. Blocks [RELB,RELB+JB): joint encoder -> jf.
__global__ __launch_bounds__(256) void k_rel3(
    const float* __restrict__ rin, const bf16* __restrict__ Wt1,
    const float* __restrict__ b1, const bf16* __restrict__ Wt2,
    const float* __restrict__ b2, const bf16* __restrict__ Wt3,
    const float* __restrict__ b3, const bf16* __restrict__ gWt,
    const float* __restrict__ sgW, const float* __restrict__ bconst,
    bf16* __restrict__ attnR, const float* __restrict__ jin,
    const bf16* __restrict__ Wj1, const float* __restrict__ jb1,
    const bf16* __restrict__ Wj2, const float* __restrict__ jb2,
    const bf16* __restrict__ Wj3, const float* __restrict__ jb3,
    float* __restrict__ jf) {
  __shared__ __align__(16) char smem[SMEM_TOT];
  bf16* x1 = (bf16*)(smem + X_OFF);
  bf16* x2 = (bf16*)(smem + X_OFF);   // alias (x1 dead after L2 loop)
  bf16* x3 = (bf16*)(smem + X_OFF);   // alias (x2 dead after L3 loop)
  bf16* Bst = (bf16*)(smem + BST_OFF);
  float* sstat = (float*)(smem + SST_OFF);
  float* sstatF = (float*)(smem + SSF_OFF);

  const int t = threadIdx.x;
  const int lane = t & 63, wv = t >> 6;
  const int lrow = lane & 15, quad = lane >> 4;
  const bool rel = blockIdx.x < RELB;

  const bf16* W1 = rel ? Wt1 : Wj1;
  const bf16* W2 = rel ? Wt2 : Wj2;
  const bf16* W3 = rel ? Wt3 : Wj3;
  const float* B1 = rel ? b1 : jb1;
  const float* B2v = rel ? b2 : jb2;

  // stage W2 half-strip: k-step k0, half h (cols wv*64+h*32 .. +32) into buffer h.
  // Buffer layout [128 local rows][32 k]; local row R maps to global col
  // G = R + wv*32 + h*32. XOR-swizzle keyed on LOCAL row (source-side pre-swizzle;
  // matching XOR on the ds_read). 2 gload16/wave/stage.
  auto stage2h = [&](int k0, int h) {
    bf16* dst = Bst + h * 4096;
#pragma unroll
    for (int c = 0; c < 2; ++c) {
      int Rb = wv * 32 + c * 16;
      int R = Rb + (lane >> 2);
      int G = R + wv * 32 + h * 32;
      int ch = (lane & 3) ^ ((R >> 1) & 3);
      gload16(&W2[(size_t)G * 256 + k0 * 32 + ch * 8], &dst[Rb * 32]);
    }
  };
  // stage W3 half-strip: K=32 slice s2 of all 128 rows' wave-private slice
  // (rows wv*32..+32) into buffer (s2&1). Local row == global row.
  auto stage3h = [&](int s2) {
    bf16* dst = Bst + (s2 & 1) * 4096;
#pragma unroll
    for (int c = 0; c < 2; ++c) {
      int Rb = wv * 32 + c * 16;
      int R = Rb + (lane >> 2);
      int ch = (lane & 3) ^ ((R >> 1) & 3);
      gload16(&W3[(size_t)R * 256 + s2 * 32 + ch * 8], &dst[Rb * 32]);
    }
  };

  stage2h(0, 0);  // first two half-strips; latency hides under x1 production
  stage2h(0, 1);

  // ---- produce whole x1 (64 rows x 256) upfront; A-frags direct from global ----
  short8 a0;       // rel: 32-wide input (26 valid)
  short8 aj[3];    // joint: 96-wide input
  if (rel) {
    const long gr = (long)blockIdx.x * 64 + wv * 16 + lrow;
    const float* ap = &rin[gr * 26];
    float v[8];
    if (quad < 3) {
#pragma unroll
      for (int u = 0; u < 4; ++u) {
        f32x2 f = *(const f32x2*)(ap + quad * 8 + u * 2);
        v[u * 2] = f[0];
        v[u * 2 + 1] = f[1];
      }
    } else {
      f32x2 f = *(const f32x2*)(ap + 24);
      v[0] = f[0];
      v[1] = f[1];
#pragma unroll
      for (int u = 2; u < 8; ++u) v[u] = 0.f;
    }
    bf16 pk[8];
#pragma unroll
    for (int u = 0; u < 8; ++u) pk[u] = __float2bfloat16(v[u]);
    a0 = *(short8*)pk;
  } else {
    const long gj = (long)(blockIdx.x - RELB) * 64 + wv * 16 + lrow;
#pragma unroll
    for (int ks = 0; ks < 3; ++ks) {
      const float* ap = &jin[gj * 96 + ks * 32 + quad * 8];
      f32x4 f0 = *(const f32x4*)ap;
      f32x4 f1 = *(const f32x4*)(ap + 4);
      bf16 pk[8];
#pragma unroll
      for (int u = 0; u < 4; ++u) {
        pk[u] = __float2bfloat16(f0[u]);
        pk[u + 4] = __float2bfloat16(f1[u]);
      }
      aj[ks] = *(short8*)pk;
    }
  }
#pragma unroll 2
  for (int ks8 = 0; ks8 < 8; ++ks8) {
#pragma unroll
    for (int ct = 0; ct < 2; ++ct) {
      f32x4 x = {0.f, 0.f, 0.f, 0.f};
      if (rel) {
        short8 bw = *(const short8*)&W1[(ks8 * 32 + ct * 16 + lrow) * 32 + quad * 8];
        x = __builtin_amdgcn_mfma_f32_16x16x32_bf16(bw, a0, x, 0, 0, 0);
      } else {
#pragma unroll
        for (int ks = 0; ks < 3; ++ks) {
          short8 bw =
              *(const short8*)&W1[(ks8 * 32 + ct * 16 + lrow) * 96 + ks * 32 + quad * 8];
          x = __builtin_amdgcn_mfma_f32_16x16x32_bf16(bw, aj[ks], x, 0, 0, 0);
        }
      }
      f32x4 bq = *(const f32x4*)&B1[ks8 * 32 + ct * 16 + quad * 4];
      bf16 pk[4];
#pragma unroll
      for (int r = 0; r < 4; ++r) pk[r] = __float2bfloat16(x[r] + bq[r]);
      *(s16x4*)&x1[(wv * 16 + lrow) * X2S + ks8 * 32 + ct * 16 + quad * 4] =
          *(s16x4*)pk;
    }
  }

  // ---- L2 (K=256): barrier-free, wave-private 2-deep half-strip pipeline ----
  f32x4 acc2[4][4];
#pragma unroll
  for (int i = 0; i < 4; ++i)
#pragma unroll
    for (int j = 0; j < 4; ++j) {
      f32x4 z = {0.f, 0.f, 0.f, 0.f};
      acc2[i][j] = z;
    }
  __syncthreads();  // x1 visible; drains stage2h(0,*) (landed during x1 phase)
#pragma unroll
  for (int k = 0; k < 8; ++k) {
    short8 af[4];
#pragma unroll
    for (int i = 0; i < 4; ++i)
      af[i] = *(const short8*)&x1[(i * 16 + lrow) * X2S + k * 32 + quad * 8];
#pragma unroll
    for (int h = 0; h < 2; ++h) {
      if (k > 0) {
        // wait own stage(k,h); leave the 2 newer loads (next half-strip) in flight
        if (k == 7 && h == 1)
          asm volatile("s_waitcnt vmcnt(0)" ::: "memory");
        else
          asm volatile("s_waitcnt vmcnt(2)" ::: "memory");
      }
      const bf16* bb = Bst + h * 4096;
      short8 bfr[2];
#pragma unroll
      for (int j2 = 0; j2 < 2; ++j2) {
        int rb = wv * 32 + j2 * 16 + lrow;
        bfr[j2] = *(const short8*)&bb[rb * 32 + ((quad ^ ((rb >> 1) & 3)) * 8)];
      }
#pragma unroll
      for (int i = 0; i < 4; ++i)
#pragma unroll
        for (int j2 = 0; j2 < 2; ++j2)
          acc2[i][h * 2 + j2] = __builtin_amdgcn_mfma_f32_16x16x32_bf16(
              bfr[j2], af[i], acc2[i][h * 2 + j2], 0, 0, 0);
      __builtin_amdgcn_sched_barrier(0);  // keep stage AFTER the consuming MFMAs
      if (k < 7) stage2h(k + 1, h);
    }
  }
  __syncthreads();  // all waves done reading x1 (x2 aliases x1)

  // issue first two W3 half-strips; they land under the x2 pack/write work
  stage3h(0);
  stage3h(1);

  // write x2 from acc2 (lane holds row i*16+lrow, cols wv*64+j*16+quad*4..+3)
#pragma unroll
  for (int i = 0; i < 4; ++i)
#pragma unroll
    for (int j = 0; j < 4; ++j) {
      f32x4 bq = *(const f32x4*)&B2v[wv * 64 + j * 16 + quad * 4];
      bf16 pk[4];
#pragma unroll
      for (int r = 0; r < 4; ++r) pk[r] = __float2bfloat16(acc2[i][j][r] + bq[r]);
      *(s16x4*)&x2[(i * 16 + lrow) * X2S + wv * 64 + j * 16 + quad * 4] = *(s16x4*)pk;
    }
  __syncthreads();  // x2 visible; drains stage3h(0/1)

  // ---- L3 (K=256, 128 cols): barrier-free, same counted-vmcnt pipeline ----
  f32x4 acc3[4][2];
#pragma unroll
  for (int i = 0; i < 4; ++i) {
    f32x4 z = {0.f, 0.f, 0.f, 0.f};
    acc3[i][0] = z;
    acc3[i][1] = z;
  }
#pragma unroll
  for (int s2 = 0; s2 < 8; ++s2) {
    short8 af[4];
#pragma unroll
    for (int i = 0; i < 4; ++i)
      af[i] = *(const short8*)&x2[(i * 16 + lrow) * X2S + s2 * 32 + quad * 8];
    if (s2 >= 2) {
      if (s2 == 7)
        asm volatile("s_waitcnt vmcnt(0)" ::: "memory");
      else
        asm volatile("s_waitcnt vmcnt(2)" ::: "memory");
    }
    const bf16* bb = Bst + (s2 & 1) * 4096;
    short8 bfr[2];
#pragma unroll
    for (int j = 0; j < 2; ++j) {
      int rb = wv * 32 + j * 16 + lrow;
      bfr[j] = *(const short8*)&bb[rb * 32 + ((quad ^ ((rb >> 1) & 3)) * 8)];
    }
#pragma unroll
    for (int i = 0; i < 4; ++i)
#pragma unroll
      for (int j = 0; j < 2; ++j)
        acc3[i][j] =
            __builtin_amdgcn_mfma_f32_16x16x32_bf16(bfr[j], af[i], acc3[i][j], 0, 0, 0);
    __builtin_amdgcn_sched_barrier(0);
    if (s2 + 2 < 8) stage3h(s2 + 2);
  }

  if (!rel) {
    const long r0j = (long)(blockIdx.x - RELB) * 64;
#pragma unroll
    for (int i = 0; i < 4; ++i)
#pragma unroll
      for (int j = 0; j < 2; ++j) {
        f32x4 bq = *(const f32x4*)&jb3[wv * 32 + j * 16 + quad * 4];
        f32x4 out;
#pragma unroll
        for (int r = 0; r < 4; ++r) out[r] = acc3[i][j][r] + bq[r];
        *(f32x4*)&jf[(r0j + i * 16 + lrow) * 128 + wv * 32 + j * 16 + quad * 4] = out;
      }
    return;
  }

  __syncthreads();  // all x2 reads done (x3 aliases x2, different stride)

  // ---- rel: x3 write (alias x2, packed b64) + LN stats (2 shfl per i) ----
#pragma unroll
  for (int i = 0; i < 4; ++i) {
    float s1 = 0.f, s2v = 0.f;
#pragma unroll
    for (int j = 0; j < 2; ++j) {
      f32x4 bq = *(const f32x4*)&b3[wv * 32 + j * 16 + quad * 4];
      bf16 pk[4];
#pragma unroll
      for (int r = 0; r < 4; ++r) {
        float v = acc3[i][j][r] + bq[r];
        pk[r] = __float2bfloat16(v);
        s1 += v;
        s2v += v * v;
      }
      *(s16x4*)&x3[(i * 16 + lrow) * X3S + wv * 32 + j * 16 + quad * 4] = *(s16x4*)pk;
    }
    s1 += __shfl_xor(s1, 16, 64);
    s2v += __shfl_xor(s2v, 16, 64);
    s1 += __shfl_xor(s1, 32, 64);
    s2v += __shfl_xor(s2v, 32, 64);
    if (quad == 0) {
      int row = i * 16 + lrow;
      sstat[(row * 4 + wv) * 2] = s1;
      sstat[(row * 4 + wv) * 2 + 1] = s2v;
    }
  }
  // hoist gemm32 A-operands (gWt, L1/L2-hot) across stats barriers
  short8 aw0[4], aw1[4];
#pragma unroll
  for (int kk = 0; kk < 4; ++kk) {
    aw0[kk] = *(const short8*)&gWt[lrow * 128 + kk * 32 + quad * 8];
    aw1[kk] = *(const short8*)&gWt[(16 + lrow) * 128 + kk * 32 + quad * 8];
  }
  __syncthreads();
  if (t < 64) {
    float s1 = 0.f, s2v = 0.f;
#pragma unroll
    for (int w = 0; w < 4; ++w) {
      s1 += sstat[(t * 4 + w) * 2];
      s2v += sstat[(t * 4 + w) * 2 + 1];
    }
    float mu = s1 * (1.f / 128.f);
    float var = s2v * (1.f / 128.f) - mu * mu;
    sstatF[t * 2] = mu;
    sstatF[t * 2 + 1] = rsqrtf(var + 1e-5f);
  }
  __syncthreads();

  // ---- gemm32: 32 out-chans x 64 rows (wave = 16 rows), LN stats trick, scatter ----
  {
    f32x4 ac0 = {0.f, 0.f, 0.f, 0.f}, ac1 = {0.f, 0.f, 0.f, 0.f};
#pragma unroll
    for (int kk = 0; kk < 4; ++kk) {
      short8 bbx = *(const short8*)&x3[(wv * 16 + lrow) * X3S + kk * 32 + quad * 8];
      ac0 = __builtin_amdgcn_mfma_f32_16x16x32_bf16(aw0[kk], bbx, ac0, 0, 0, 0);
      ac1 = __builtin_amdgcn_mfma_f32_16x16x32_bf16(aw1[kk], bbx, ac1, 0, 0, 0);
    }
    const long r0 = (long)blockIdx.x * 64;
    int drow = wv * 16 + lrow;
    long gr = r0 + drow;
    float mu = sstatF[drow * 2], inv = sstatF[drow * 2 + 1];
    int bb_ = (int)(gr >> 16);
    int nn = (int)((gr >> 8) & 255);
    int mm = (int)(gr & 255);
#pragma unroll
    for (int mt = 0; mt < 2; ++mt) {
      f32x4 a = mt ? ac1 : ac0;
#pragma unroll
      for (int reg = 0; reg < 4; ++reg) {
        int col = mt * 16 + quad * 4 + reg;
        float v = inv * (a[reg] - mu * sgW[col]) + bconst[col];
        int dd = col >> 3, hh = col & 7;
        attnR[((((long)dd * Bb + bb_) * Hh + hh) * Nn + nn) * Nn + mm] =
            __float2bfloat16(v);
      }
    }
  }
}

// =============== MFMA GEMM (generic, LDS-staged): decoder 2/3 ===============
template <typename TA, typename TC, bool GELU, bool RESID>
__global__ __launch_bounds__(256) void k_gemm_mfma(
    const TA* __restrict__ A, int Ka, int Kp, const bf16* __restrict__ Bt,
    const float* __restrict__ bias, TC* __restrict__ C, int ldc, int ncols,
    const float* __restrict__ resid) {
  __shared__ __align__(16) bf16 sA[128 * 32];
  __shared__ __align__(16) bf16 sB[128 * 32];
  const int t = threadIdx.x;
  const int lane = t & 63;
  const int wv = t >> 6;
  const int wr = wv >> 1, wc = wv & 1;
  const int lrow = lane & 15, quad = lane >> 4;
  const long row0 = (long)blockIdx.y * 128;
  const int n0 = blockIdx.x * 128;
  const int rg = lane >> 2;
  const int kE = (lane & 3) * 8;

  f32x4 zero = {0.f, 0.f, 0.f, 0.f};
  f32x4 acc[4][4];
#pragma unroll
  for (int i = 0; i < 4; ++i)
#pragma unroll
    for (int j = 0; j < 4; ++j) acc[i][j] = zero;

  for (int k0 = 0; k0 < Kp; k0 += 32) {
    {
      const int r0 = wv * 32;
      gload16(&Bt[(long)(n0 + r0 + rg) * Kp + k0 + kE], &sB[r0 * 32]);
      gload16(&Bt[(long)(n0 + r0 + 16 + rg) * Kp + k0 + kE], &sB[(r0 + 16) * 32]);
    }
    if (sizeof(TA) == 2) {
      const int r0 = wv * 32;
      gload16((const bf16*)&A[(row0 + r0 + rg) * (long)Ka + k0 + kE], &sA[r0 * 32]);
      gload16((const bf16*)&A[(row0 + r0 + 16 + rg) * (long)Ka + k0 + kE],
              &sA[(r0 + 16) * 32]);
    } else {
      for (int idx = t; idx < 128 * 32; idx += 256) {
        int r = idx >> 5, k = idx & 31;
        int gk = k0 + k;
        float v = (gk < Ka) ? toF(A[(row0 + r) * (long)Ka + gk]) : 0.f;
        sA[idx] = __float2bfloat16(v);
      }
    }
    __syncthreads();
    short8 af[4], bfr[4];
#pragma unroll
    for (int i = 0; i < 4; ++i)
      af[i] = *(const short8*)&sA[(wr * 64 + i * 16 + lrow) * 32 + quad * 8];
#pragma unroll
    for (int j = 0; j < 4; ++j)
      bfr[j] = *(const short8*)&sB[(wc * 64 + j * 16 + lrow) * 32 + quad * 8];
#pragma unroll
    for (int i = 0; i < 4; ++i)
#pragma unroll
      for (int j = 0; j < 4; ++j)
        acc[i][j] =
            __builtin_amdgcn_mfma_f32_16x16x32_bf16(af[i], bfr[j], acc[i][j], 0, 0, 0);
    __syncthreads();
  }

#pragma unroll
  for (int i = 0; i < 4; ++i) {
#pragma unroll
    for (int r = 0; r < 4; ++r) {
      int rl = wr * 64 + i * 16 + quad * 4 + r;
      long gr = row0 + rl;
#pragma unroll
      for (int j = 0; j < 4; ++j) {
        int gc = n0 + wc * 64 + j * 16 + lrow;
        if (gc < ncols) {
          float v = acc[i][j][r] + bias[gc];
          if (GELU) v = 0.5f * v * (1.f + erff(v * 0.70710678118654752f));
          if (RESID) v += resid[gr * (long)ldc + gc];
          stF(&C[gr * (long)ldc + gc], v);
        }
      }
    }
  }
}

// =============== k_lnqkv: row-LN (dim 128) fused into K=128 GEMM, 32-row blocks ===============
template <typename TC>
__global__ __launch_bounds__(256) void k_lnqkv(
    const float* __restrict__ A, const float* __restrict__ g,
    const float* __restrict__ b, const bf16* __restrict__ Bt,
    const float* __restrict__ bias, TC* __restrict__ C, int ldc, int ncols) {
  __shared__ __align__(16) bf16 sX[32 * XTS];
  const int t = threadIdx.x;
  const int lane = t & 63;
  const int wv = t >> 6;
  const int lrow = lane & 15, quad = lane >> 4;
  const long row0 = (long)blockIdx.y * 32;
  const int n0 = blockIdx.x * 128;

  {
    int row = t >> 3, prt = t & 7;
    const float* ap = &A[(row0 + row) * 128 + prt * 16];
    float v[16];
    float s1 = 0.f, s2 = 0.f;
#pragma unroll
    for (int u = 0; u < 4; ++u) {
      f32x4 q = *(const f32x4*)(ap + u * 4);
#pragma unroll
      for (int e = 0; e < 4; ++e) {
        v[u * 4 + e] = q[e];
        s1 += q[e];
        s2 += q[e] * q[e];
      }
    }
    s1 += __shfl_xor(s1, 1, 64);
    s2 += __shfl_xor(s2, 1, 64);
    s1 += __shfl_xor(s1, 2, 64);
    s2 += __shfl_xor(s2, 2, 64);
    s1 += __shfl_xor(s1, 4, 64);
    s2 += __shfl_xor(s2, 4, 64);
    float mu = s1 * (1.f / 128.f);
    float inv = rsqrtf(s2 * (1.f / 128.f) - mu * mu + 1e-5f);
#pragma unroll
    for (int u4 = 0; u4 < 4; ++u4) {
      bf16 pk[4];
#pragma unroll
      for (int e = 0; e < 4; ++e) {
        int c = prt * 16 + u4 * 4 + e;
        pk[e] = __float2bfloat16((v[u4 * 4 + e] - mu) * inv * g[c] + b[c]);
      }
      *(s16x4*)&sX[row * XTS + prt * 16 + u4 * 4] = *(s16x4*)pk;
    }
  }
  __syncthreads();

  f32x4 acc[2][2];
#pragma unroll
  for (int i = 0; i < 2; ++i)
#pragma unroll
    for (int j = 0; j < 2; ++j) {
      f32x4 z = {0.f, 0.f, 0.f, 0.f};
      acc[i][j] = z;
    }
#pragma unroll
  for (int k0 = 0; k0 < 128; k0 += 32) {
    short8 af[2], bfr[2];
#pragma unroll
    for (int j = 0; j < 2; ++j)
      bfr[j] = *(const short8*)&Bt[(long)(n0 + wv * 32 + j * 16 + lrow) * 128 + k0 +
                                   quad * 8];
#pragma unroll
    for (int i = 0; i < 2; ++i)
      af[i] = *(const short8*)&sX[(i * 16 + lrow) * XTS + k0 + quad * 8];
#pragma unroll
    for (int i = 0; i < 2; ++i)
#pragma unroll
      for (int j = 0; j < 2; ++j)
        acc[i][j] =
            __builtin_amdgcn_mfma_f32_16x16x32_bf16(af[i], bfr[j], acc[i][j], 0, 0, 0);
  }
#pragma unroll
  for (int i = 0; i < 2; ++i) {
#pragma unroll
    for (int r = 0; r < 4; ++r) {
      long gr = row0 + i * 16 + quad * 4 + r;
#pragma unroll
      for (int j = 0; j < 2; ++j) {
        int gc = n0 + wv * 32 + j * 16 + lrow;
        if (gc < ncols) stF(&C[gr * (long)ldc + gc], acc[i][j][r] + bias[gc]);
      }
    }
  }
}

// =============== k_tailq: proj+resid -> LN3 -> MLP(+gelu) -> resid [-> LN1' + QKV'] ===============
// 16-row blocks (grid 128): 2x machine coverage vs 32-row/grid-64.
template <bool QKV>
__global__ __launch_bounds__(256) void k_tailq(
    const bf16* __restrict__ obuf, float* __restrict__ jf, const bf16* __restrict__ Wp,
    const float* __restrict__ pb, const float* __restrict__ g3,
    const float* __restrict__ b3, const bf16* __restrict__ Wm1,
    const float* __restrict__ m1b, const bf16* __restrict__ Wm2,
    const float* __restrict__ m2b, const float* __restrict__ g1n,
    const float* __restrict__ b1n, const bf16* __restrict__ Wqn,
    const float* __restrict__ qbn, float* __restrict__ qkvb) {
  __shared__ __align__(16) bf16 sX[16 * XTS];
  __shared__ __align__(16) bf16 sH[16 * XTS];
  __shared__ float sstat[16][4][2];
  __shared__ float sstatF[16][2];

  const int t = threadIdx.x;
  const int lane = t & 63;
  const int wv = t >> 6;
  const int lrow = lane & 15, quad = lane >> 4;
  const long row0 = (long)blockIdx.x * 16;

  {
    int r = t >> 4, c8 = (t & 15) * 8;
    *(uint4*)&sX[r * XTS + c8] = *(const uint4*)&obuf[(row0 + r) * 128 + c8];
  }
  __syncthreads();

  // ---- proj GEMM (16x128, K=128), wave n-split 32 ----
  f32x4 acc[2];
  {
    f32x4 z = {0.f, 0.f, 0.f, 0.f};
    acc[0] = z;
    acc[1] = z;
  }
#pragma unroll
  for (int k0 = 0; k0 < 128; k0 += 32) {
    short8 af = *(const short8*)&sX[lrow * XTS + k0 + quad * 8];
    short8 bfr[2];
#pragma unroll
    for (int j = 0; j < 2; ++j)
      bfr[j] = *(const short8*)&Wp[(wv * 32 + j * 16 + lrow) * 128 + k0 + quad * 8];
#pragma unroll
    for (int j = 0; j < 2; ++j)
      acc[j] = __builtin_amdgcn_mfma_f32_16x16x32_bf16(af, bfr[j], acc[j], 0, 0, 0);
  }
#pragma unroll
  for (int r = 0; r < 4; ++r) {
    int rl = quad * 4 + r;
    long gr = row0 + rl;
    float s1 = 0.f, s2 = 0.f;
#pragma unroll
    for (int j = 0; j < 2; ++j) {
      int gc = wv * 32 + j * 16 + lrow;
      float v = acc[j][r] + pb[gc] + jf[gr * 128 + gc];
      acc[j][r] = v;
      jf[gr * 128 + gc] = v;
      s1 += v;
      s2 += v * v;
    }
#pragma unroll
    for (int m = 1; m < 16; m <<= 1) {
      s1 += __shfl_xor(s1, m, 64);
      s2 += __shfl_xor(s2, m, 64);
    }
    if (lrow == 0) {
      sstat[rl][wv][0] = s1;
      sstat[rl][wv][1] = s2;
    }
  }
  __syncthreads();
  if (t < 16) {
    float s1 = 0.f, s2 = 0.f;
#pragma unroll
    for (int w = 0; w < 4; ++w) {
      s1 += sstat[t][w][0];
      s2 += sstat[t][w][1];
    }
    float mu = s1 * (1.f / 128.f);
    float var = s2 * (1.f / 128.f) - mu * mu;
    sstatF[t][0] = mu;
    sstatF[t][1] = rsqrtf(var + 1e-5f);
  }
  __syncthreads();
#pragma unroll
  for (int r = 0; r < 4; ++r) {
    int rl = quad * 4 + r;
    float mu = sstatF[rl][0], inv = sstatF[rl][1];
#pragma unroll
    for (int j = 0; j < 2; ++j) {
      int gc = wv * 32 + j * 16 + lrow;
      sX[rl * XTS + gc] = __float2bfloat16((acc[j][r] - mu) * inv * g3[gc] + b3[gc]);
    }
  }
  __syncthreads();

  // ---- MLP1 + gelu ----
  f32x4 acc2[2];
  {
    f32x4 z = {0.f, 0.f, 0.f, 0.f};
    acc2[0] = z;
    acc2[1] = z;
  }
#pragma unroll
  for (int k0 = 0; k0 < 128; k0 += 32) {
    short8 af = *(const short8*)&sX[lrow * XTS + k0 + quad * 8];
    short8 bfr[2];
#pragma unroll
    for (int j = 0; j < 2; ++j)
      bfr[j] = *(const short8*)&Wm1[(wv * 32 + j * 16 + lrow) * 128 + k0 + quad * 8];
#pragma unroll
    for (int j = 0; j < 2; ++j)
      acc2[j] = __builtin_amdgcn_mfma_f32_16x16x32_bf16(af, bfr[j], acc2[j], 0, 0, 0);
  }
#pragma unroll
  for (int r = 0; r < 4; ++r) {
    int rl = quad * 4 + r;
#pragma unroll
    for (int j = 0; j < 2; ++j) {
      int gc = wv * 32 + j * 16 + lrow;
      float v = acc2[j][r] + m1b[gc];
      v = 0.5f * v * (1.f + erff(v * 0.70710678118654752f));
      sH[rl * XTS + gc] = __float2bfloat16(v);
    }
  }
  __syncthreads();

  // ---- MLP2 + resid [+ stats] ----
  f32x4 acc3[2];
  {
    f32x4 z = {0.f, 0.f, 0.f, 0.f};
    acc3[0] = z;
    acc3[1] = z;
  }
#pragma unroll
  for (int k0 = 0; k0 < 128; k0 += 32) {
    short8 af = *(const short8*)&sH[lrow * XTS + k0 + quad * 8];
    short8 bfr[2];
#pragma unroll
    for (int j = 0; j < 2; ++j)
      bfr[j] = *(const short8*)&Wm2[(wv * 32 + j * 16 + lrow) * 128 + k0 + quad * 8];
#pragma unroll
    for (int j = 0; j < 2; ++j)
      acc3[j] = __builtin_amdgcn_mfma_f32_16x16x32_bf16(af, bfr[j], acc3[j], 0, 0, 0);
  }
#pragma unroll
  for (int r = 0; r < 4; ++r) {
    int rl = quad * 4 + r;
    long gr = row0 + rl;
    float s1 = 0.f, s2 = 0.f;
#pragma unroll
    for (int j = 0; j < 2; ++j) {
      int gc = wv * 32 + j * 16 + lrow;
      float v = acc3[j][r] + m2b[gc] + jf[gr * 128 + gc];
      acc3[j][r] = v;
      jf[gr * 128 + gc] = v;
      if (QKV) {
        s1 += v;
        s2 += v * v;
      }
    }
    if (QKV) {
#pragma unroll
      for (int m = 1; m < 16; m <<= 1) {
        s1 += __shfl_xor(s1, m, 64);
        s2 += __shfl_xor(s2, m, 64);
      }
      if (lrow == 0) {
        sstat[rl][wv][0] = s1;
        sstat[rl][wv][1] = s2;
      }
    }
  }
  if (!QKV) return;
  __syncthreads();
  if (t < 16) {
    float s1 = 0.f, s2 = 0.f;
#pragma unroll
    for (int w = 0; w < 4; ++w) {
      s1 += sstat[t][w][0];
      s2 += sstat[t][w][1];
    }
    float mu = s1 * (1.f / 128.f);
    float var = s2 * (1.f / 128.f) - mu * mu;
    sstatF[t][0] = mu;
    sstatF[t][1] = rsqrtf(var + 1e-5f);
  }
  __syncthreads();
#pragma unroll
  for (int r = 0; r < 4; ++r) {
    int rl = quad * 4 + r;
    float mu = sstatF[rl][0], inv = sstatF[rl][1];
#pragma unroll
    for (int j = 0; j < 2; ++j) {
      int gc = wv * 32 + j * 16 + lrow;
      sX[rl * XTS + gc] = __float2bfloat16((acc3[j][r] - mu) * inv * g1n[gc] + b1n[gc]);
    }
  }
  __syncthreads();
  for (int p = 0; p < 3; ++p) {
    f32x4 acc4[2];
    {
      f32x4 z = {0.f, 0.f, 0.f, 0.f};
      acc4[0] = z;
      acc4[1] = z;
    }
#pragma unroll
    for (int k0 = 0; k0 < 128; k0 += 32) {
      short8 af = *(const short8*)&sX[lrow * XTS + k0 + quad * 8];
      short8 bfr[2];
#pragma unroll
      for (int j = 0; j < 2; ++j)
        bfr[j] = *(const short8*)&Wqn[(long)(p * 128 + wv * 32 + j * 16 + lrow) * 128 +
                                      k0 + quad * 8];
#pragma unroll
      for (int j = 0; j < 2; ++j)
        acc4[j] = __builtin_amdgcn_mfma_f32_16x16x32_bf16(af, bfr[j], acc4[j], 0, 0, 0);
    }
#pragma unroll
    for (int r = 0; r < 4; ++r) {
      long gr = row0 + quad * 4 + r;
#pragma unroll
      for (int j = 0; j < 2; ++j) {
        int gc = p * 128 + wv * 32 + j * 16 + lrow;
        qkvb[gr * 384 + gc] = acc4[j][r] + qbn[gc];
      }
    }
  }
}

// ---- prep: transpose+cast all weights to bf16 [col][K]; build gW / sgW / bconst ----
__global__ void k_prep(const float* re_w1, const float* re_w2, const float* re_w3,
                       const float* ln2_g, const float* ln2_b, const float* rconv_w,
                       const float* rconv_b, const float* je_w1, const float* je_w2,
                       const float* je_w3, const float* qkv_w, const float* proj_w,
                       const float* mw1, const float* mw2, const float* dw1,
                       const float* dw2, const float* dw3, bf16* Wt1, bf16* Wt2,
                       bf16* Wt3, bf16* gWt, float* sgW, float* bconst, bf16* Wj1,
                       bf16* Wj2, bf16* Wj3, bf16* Wq, bf16* Wp, bf16* Wm1, bf16* Wm2,
                       bf16* Wd1, bf16* Wd2, bf16* Wd3) {
  const int stride = gridDim.x * blockDim.x;
  const int tid = blockIdx.x * blockDim.x + threadIdx.x;
  for (int i = tid; i < 256 * 32; i += stride) {
    int n = i >> 5, k = i & 31;
    Wt1[i] = __float2bfloat16(k < 26 ? re_w1[k * 256 + n] : 0.f);
  }
  for (int i = tid; i < 256 * 256; i += stride) {
    int n = i >> 8, k = i & 255;
    Wt2[i] = __float2bfloat16(re_w2[k * 256 + n]);
  }
  for (int i = tid; i < 128 * 256; i += stride) {
    int n = i >> 8, k = i & 255;
    Wt3[i] = __float2bfloat16(re_w3[k * 128 + n]);
  }
  for (int i = tid; i < 32 * 128; i += stride) {
    int col = i >> 7, c = i & 127;
    int dd = col >> 3, h = col & 7;
    gWt[i] = __float2bfloat16(ln2_g[dd * 128 + c] * rconv_w[(dd * 128 + c) * 8 + h]);
  }
  if (tid < 32) {
    int dd = tid >> 3, h = tid & 7;
    float sg = 0.f, bc = 0.f;
    for (int c = 0; c < 128; ++c) {
      float w = rconv_w[(dd * 128 + c) * 8 + h];
      sg += ln2_g[dd * 128 + c] * w;
      bc += ln2_b[dd * 128 + c] * w;
    }
    sgW[tid] = sg;
    bconst[tid] = bc + rconv_b[tid];
  }
  for (int i = tid; i < 256 * 96; i += stride) {
    int n = i / 96, k = i - n * 96;
    Wj1[i] = __float2bfloat16(je_w1[k * 256 + n]);
  }
  for (int i = tid; i < 256 * 256; i += stride) {
    int n = i >> 8, k = i & 255;
    Wj2[i] = __float2bfloat16(je_w2[k * 256 + n]);
  }
  for (int i = tid; i < 128 * 256; i += stride) {
    int n = i >> 8, k = i & 255;
    Wj3[i] = __float2bfloat16(je_w3[k * 128 + n]);
  }
  for (int i = tid; i < 4 * 384 * 128; i += stride) {
    int d = i / 49152, rem = i - d * 49152;
    int n = rem >> 7, k = rem & 127;
    Wq[i] = __float2bfloat16(qkv_w[d * 49152 + k * 384 + n]);
  }
  for (int i = tid; i < 4 * 128 * 128; i += stride) {
    int d = i >> 14, rem = i & 16383;
    int n = rem >> 7, k = rem & 127;
    Wp[i] = __float2bfloat16(proj_w[d * 16384 + k * 128 + n]);
    Wm1[i] = __float2bfloat16(mw1[d * 16384 + k * 128 + n]);
    Wm2[i] = __float2bfloat16(mw2[d * 16384 + k * 128 + n]);
  }
  for (int i = tid; i < 256 * 128; i += stride) {
    int n = i >> 7, k = i & 127;
    Wd1[i] = __float2bfloat16(dw1[k * 256 + n]);
  }
  for (int i = tid; i < 512 * 256; i += stride) {
    int n = i >> 8, k = i & 255;
    Wd2[i] = __float2bfloat16(dw2[k * 512 + n]);
  }
  for (int i = tid; i < 128 * 512; i += stride) {
    int n = i >> 9, k = i & 511;
    Wd3[i] = __float2bfloat16(n < 90 ? dw3[k * 90 + n] : 0.f);
  }
}

// ---- fused attention: 4 independent waves per block, one wave per (b,h,n) ----
__global__ __launch_bounds__(256) void k_attn(const float* __restrict__ qkv,
                                              const bf16* __restrict__ aR,
                                              const float* __restrict__ conn,
                                              bf16* __restrict__ obuf) {
  __shared__ float p[4][4 * 68];
  const int wv = threadIdx.x >> 6;
  const int n = blockIdx.x * 4 + wv;
  const int h = blockIdx.y, b = blockIdx.z;
  const int lane = threadIdx.x & 63;
  const long rowq = (long)(b * Nn + n);
  const float* qp = &qkv[rowq * 384 + h * 16];
  f32x4 q0 = *(const f32x4*)qp;
  f32x4 q1 = *(const f32x4*)(qp + 4);
  f32x4 q2 = *(const f32x4*)(qp + 8);
  f32x4 q3 = *(const f32x4*)(qp + 12);
  const bf16* arp = &aR[((long)(b * Hh + h) * Nn + n) * Nn];
  const float* cnp = &conn[rowq * Nn];

  float lg[4];
#pragma unroll
  for (int s = 0; s < 4; ++s) {
    int m = s * 64 + lane;
    const float* kp = &qkv[((long)(b * Nn + m)) * 384 + 128 + h * 16];
    f32x4 k0 = *(const f32x4*)kp;
    f32x4 k1 = *(const f32x4*)(kp + 4);
    f32x4 k2 = *(const f32x4*)(kp + 8);
    f32x4 k3 = *(const f32x4*)(kp + 12);
    float d = 0.f;
#pragma unroll
    for (int e = 0; e < 4; ++e)
      d += q0[e] * k0[e] + q1[e] * k1[e] + q2[e] * k2[e] + q3[e] * k3[e];
    d += __bfloat162float(arp[m]);
    lg[s] = d * cnp[m] * 0.25f;
  }
  float mx = fmaxf(fmaxf(lg[0], lg[1]), fmaxf(lg[2], lg[3]));
#pragma unroll
  for (int off = 32; off; off >>= 1) mx = fmaxf(mx, __shfl_xor(mx, off, 64));
  float ex[4], ssum = 0.f;
#pragma unroll
  for (int s = 0; s < 4; ++s) {
    ex[s] = expf(lg[s] - mx);
    ssum += ex[s];
  }
#pragma unroll
  for (int off = 32; off; off >>= 1) ssum += __shfl_xor(ssum, off, 64);
#pragma unroll
  for (int s = 0; s < 4; ++s) p[wv][s * 68 + lane] = ex[s];
  float rinv = 1.f / ssum;

  const int c = lane & 15, sg = lane >> 4;
  const float* vp = &qkv[((long)(b * Nn + sg * 64)) * 384 + 256 + h * 16 + c];
  float acc = 0.f;
#pragma unroll
  for (int u = 0; u < 16; ++u) {
    f32x4 pq = *(const f32x4*)&p[wv][sg * 68 + u * 4];
#pragma unroll
    for (int e = 0; e < 4; ++e) acc += pq[e] * vp[(long)(u * 4 + e) * 384];
  }
  acc += __shfl_xor(acc, 16, 64);
  acc += __shfl_xor(acc, 32, 64);
  if (lane < 16) obuf[rowq * 128 + h * 16 + lane] = __float2bfloat16(acc * rinv);
}

extern "C" void kernel_launch(void* const* d_in, const int* in_sizes, int n_in,
                              void* d_out, int out_size, void* d_ws, size_t ws_size,
                              hipStream_t stream) {
  const float* joint_in = (const float*)d_in[0];
  const float* relation_in = (const float*)d_in[1];
  const float* conn = (const float*)d_in[2];
  const float* je_w1 = (const float*)d_in[3];
  const float* je_b1 = (const float*)d_in[4];
  const float* je_w2 = (const float*)d_in[5];
  const float* je_b2 = (const float*)d_in[6];
  const float* je_w3 = (const float*)d_in[7];
  const float* je_b3 = (const float*)d_in[8];
  const float* re_w1 = (const float*)d_in[9];
  const float* re_b1 = (const float*)d_in[10];
  const float* re_w2 = (const float*)d_in[11];
  const float* re_b2 = (const float*)d_in[12];
  const float* re_w3 = (const float*)d_in[13];
  const float* re_b3 = (const float*)d_in[14];
  const float* qkv_w = (const float*)d_in[15];
  const float* qkv_b = (const float*)d_in[16];
  const float* rconv_w = (const float*)d_in[17];
  const float* rconv_b = (const float*)d_in[18];
  const float* proj_w = (const float*)d_in[19];
  const float* proj_b = (const float*)d_in[20];
  const float* ln1_g = (const float*)d_in[21];
  const float* ln1_b = (const float*)d_in[22];
  const float* ln2_g = (const float*)d_in[23];
  const float* ln2_b = (const float*)d_in[24];
  const float* ln3_g = (const float*)d_in[25];
  const float* ln3_b = (const float*)d_in[26];
  const float* mw1 = (const float*)d_in[27];
  const float* mb1 = (const float*)d_in[28];
  const float* mw2 = (const float*)d_in[29];
  const float* mb2 = (const float*)d_in[30];
  const float* ng = (const float*)d_in[31];
  const float* nb = (const float*)d_in[32];
  const float* dw1 = (const float*)d_in[33];
  const float* db1 = (const float*)d_in[34];
  const float* dw2 = (const float*)d_in[35];
  const float* db2 = (const float*)d_in[36];
  const float* dw3 = (const float*)d_in[37];
  const float* db3 = (const float*)d_in[38];

  char* ws = (char*)d_ws;
  size_t off = 0;
  auto alloc = [&](size_t bytes) -> void* {
    void* p = ws + off;
    off += (bytes + 255) & ~(size_t)255;
    return p;
  };
  bf16* attnR = (bf16*)alloc((size_t)DEPTHd * Bb * Hh * Nn * Nn * 2);
  bf16* Wt1 = (bf16*)alloc(256 * 32 * 2);
  bf16* Wt2 = (bf16*)alloc(256 * 256 * 2);
  bf16* Wt3 = (bf16*)alloc(128 * 256 * 2);
  bf16* gWt = (bf16*)alloc(32 * 128 * 2);
  float* sgW = (float*)alloc(32 * 4);
  float* bconst = (float*)alloc(32 * 4);
  bf16* Wj1 = (bf16*)alloc(256 * 96 * 2);
  bf16* Wj2 = (bf16*)alloc(256 * 256 * 2);
  bf16* Wj3 = (bf16*)alloc(128 * 256 * 2);
  bf16* Wq = (bf16*)alloc(4 * 384 * 128 * 2);
  bf16* Wp = (bf16*)alloc(4 * 128 * 128 * 2);
  bf16* Wm1 = (bf16*)alloc(4 * 128 * 128 * 2);
  bf16* Wm2 = (bf16*)alloc(4 * 128 * 128 * 2);
  bf16* Wd1 = (bf16*)alloc(256 * 128 * 2);
  bf16* Wd2 = (bf16*)alloc(512 * 256 * 2);
  bf16* Wd3 = (bf16*)alloc(128 * 512 * 2);
  float* jf = (float*)alloc((size_t)BN * 128 * 4);
  bf16* obuf = (bf16*)alloc((size_t)BN * 128 * 2);
  char* U = (char*)alloc((size_t)BN * 384 * 4);
  float* qkvb = (float*)U;
  bf16* u1 = (bf16*)U;
  bf16* u2 = (bf16*)(U + (size_t)BN * 256 * 2);

  k_prep<<<dim3(768), dim3(256), 0, stream>>>(
      re_w1, re_w2, re_w3, ln2_g, ln2_b, rconv_w, rconv_b, je_w1, je_w2, je_w3,
      qkv_w, proj_w, mw1, mw2, dw1, dw2, dw3, Wt1, Wt2, Wt3, gWt, sgW, bconst,
      Wj1, Wj2, Wj3, Wq, Wp, Wm1, Wm2, Wd1, Wd2, Wd3);

  // relation encoder (fills attnR) + joint encoder (fills jf)
  k_rel3<<<dim3(RELB + JB), dim3(256), 0, stream>>>(
      relation_in, Wt1, re_b1, Wt2, re_b2, Wt3, re_b3, gWt, sgW, bconst, attnR,
      joint_in, Wj1, je_b1, Wj2, je_b2, Wj3, je_b3, jf);

  // depth 0 QKV
  k_lnqkv<float><<<dim3(3, 64), dim3(256), 0, stream>>>(
      jf, ln1_g, ln1_b, Wq, qkv_b, qkvb, 384, 384);

  for (int d = 0; d < DEPTHd; ++d) {
    k_attn<<<dim3(Nn / 4, Hh, Bb), dim3(256), 0, stream>>>(
        qkvb, attnR + (size_t)d * Bb * Hh * Nn * Nn, conn, obuf);
    if (d < 3) {
      k_tailq<true><<<dim3(128), dim3(256), 0, stream>>>(
          obuf, jf, Wp + (size_t)d * 16384, proj_b + d * 128, ln3_g + d * 128,
          ln3_b + d * 128, Wm1 + (size_t)d * 16384, mb1 + d * 128,
          Wm2 + (size_t)d * 16384, mb2 + d * 128, ln1_g + (d + 1) * 128,
          ln1_b + (d + 1) * 128, Wq + (size_t)(d + 1) * 49152, qkv_b + (d + 1) * 384,
          qkvb);
    } else {
      k_tailq<false><<<dim3(128), dim3(256), 0, stream>>>(
          obuf, jf, Wp + (size_t)d * 16384, proj_b + d * 128, ln3_g + d * 128,
          ln3_b + d * 128, Wm1 + (size_t)d * 16384, mb1 + d * 128,
          Wm2 + (size_t)d * 16384, mb2 + d * 128, nullptr, nullptr, nullptr, nullptr,
          nullptr);
    }
  }

  // final LN fused into decoder layer 1; then 256 -> 512 -> 90
  k_lnqkv<bf16><<<dim3(2, 64), dim3(256), 0, stream>>>(jf, ng, nb, Wd1, db1, u1, 256,
                                                       256);
  k_gemm_mfma<bf16, bf16, false, false><<<dim3(4, 16), dim3(256), 0, stream>>>(
      u1, 256, 256, Wd2, db2, u2, 512, 512, nullptr);
  k_gemm_mfma<bf16, float, false, false><<<dim3(1, 16), dim3(256), 0, stream>>>(
      u2, 512, 512, Wd3, db3, (float*)d_out, 90, 90, nullptr);
}

// Round 8
// 674.346 us; speedup vs baseline: 1.0310x; 1.0310x over previous
//
#include <hip/hip_runtime.h>
#include <hip/hip_bf16.h>
#include <math.h>

typedef __hip_bfloat16 bf16;
typedef __attribute__((ext_vector_type(8))) short short8;
typedef __attribute__((ext_vector_type(4))) short s16x4;
typedef __attribute__((ext_vector_type(4))) float f32x4;
typedef __attribute__((ext_vector_type(2))) float f32x2;

#define Bb 8
#define Nn 256
#define Hh 8
#define DEPTHd 4
#define BN 2048
#define RTOT 524288
#define RELB 8192          // RTOT/64 relation blocks
#define JB 32              // BN/64 joint blocks
#define PREPB 64           // weight-prep tail blocks folded into k_rel3 dispatch
#define XTS 136

// k_rel3 LDS layout (bytes) -- ROUND-3 PROVEN LAYOUT (237us, MfmaUtil 21.5).
// Single x-region [64][264] holds x1, then x2 (aliases after L2 loop), then x3.
#define X_OFF 0            // [64][264] bf16 = 33792
#define BST_OFF 33792      // 16384 staging
#define SST_OFF 50176      // [64][4][2] f32 = 2048
#define SSF_OFF 52224      // [64][2] f32 = 512
#define SMEM_TOT 52736     // 3 blocks/CU
#define X2S 264
#define X3S 136

__device__ inline float toF(float v) { return v; }
__device__ inline float toF(bf16 v) { return __bfloat162float(v); }
__device__ inline void stF(float* p, float v) { *p = v; }
__device__ inline void stF(bf16* p, float v) { *p = __float2bfloat16(v); }

__device__ inline void gload16(const bf16* g, bf16* l) {
  __builtin_amdgcn_global_load_lds(
      (const __attribute__((address_space(1))) unsigned int*)g,
      (__attribute__((address_space(3))) unsigned int*)l, 16, 0, 0);
}

// =============== k_rel3: relation encoder, fused 3-layer MLP + LN + 1x1conv ===============
// ROUND-3 STRUCTURE (proven 237us twice; rounds 4/5/7 structural variants all lost:
// direct-global B 312/331us, counted-vmcnt wave-private pipeline 262us -- the
// barrier-amortized block-cooperative staging is this kernel's local optimum).
// x1 produced ENTIRELY UPFRONT (per-lane A-frags direct from global; same frag
// reused by all 8 k-strips) -> L2 loop is pure consume+stage, 2 barriers/strip.
// Bst staged async via global_load_lds, reads XOR-swizzled both-sides (rule #21).
// MFMA operands SWAPPED (D = W_frag * X_frag): lane's 4 acc regs = 4 consecutive
// output cols of one row -> packed b64 LDS writes / f32x4 bias loads.
// Blocks [0,RELB): relation -> attnR. [RELB,RELB+JB): joint encoder -> jf.
// [RELB+JB,RELB+JB+PREPB): LATE WEIGHT PREP (Wq/Wp/Wm/Wd transposes) -- these are
// consumed only by kernels AFTER k_rel3, so they ride the tail of this dispatch
// on CUs idled by the main-path drain, cutting k_prep's serial time ~70%.
__global__ __launch_bounds__(256) void k_rel3(
    const float* __restrict__ rin, const bf16* __restrict__ Wt1,
    const float* __restrict__ b1, const bf16* __restrict__ Wt2,
    const float* __restrict__ b2, const bf16* __restrict__ Wt3,
    const float* __restrict__ b3, const bf16* __restrict__ gWt,
    const float* __restrict__ sgW, const float* __restrict__ bconst,
    bf16* __restrict__ attnR, const float* __restrict__ jin,
    const bf16* __restrict__ Wj1, const float* __restrict__ jb1,
    const bf16* __restrict__ Wj2, const float* __restrict__ jb2,
    const bf16* __restrict__ Wj3, const float* __restrict__ jb3,
    float* __restrict__ jf,
    const float* __restrict__ qkv_w, const float* __restrict__ proj_w,
    const float* __restrict__ mw1, const float* __restrict__ mw2,
    const float* __restrict__ dw1, const float* __restrict__ dw2,
    const float* __restrict__ dw3, bf16* __restrict__ Wq, bf16* __restrict__ Wp,
    bf16* __restrict__ Wm1, bf16* __restrict__ Wm2, bf16* __restrict__ Wd1,
    bf16* __restrict__ Wd2, bf16* __restrict__ Wd3) {
  const int t = threadIdx.x;

  // ---- late weight-prep tail blocks (no LDS, no barriers; return early) ----
  if (blockIdx.x >= RELB + JB) {
    const int stride = PREPB * 256;
    const int tid = (blockIdx.x - (RELB + JB)) * 256 + t;
    for (int i = tid; i < 4 * 384 * 128; i += stride) {
      int d = i / 49152, rem = i - d * 49152;
      int n = rem >> 7, k = rem & 127;
      Wq[i] = __float2bfloat16(qkv_w[d * 49152 + k * 384 + n]);
    }
    for (int i = tid; i < 4 * 128 * 128; i += stride) {
      int d = i >> 14, rem = i & 16383;
      int n = rem >> 7, k = rem & 127;
      Wp[i] = __float2bfloat16(proj_w[d * 16384 + k * 128 + n]);
      Wm1[i] = __float2bfloat16(mw1[d * 16384 + k * 128 + n]);
      Wm2[i] = __float2bfloat16(mw2[d * 16384 + k * 128 + n]);
    }
    for (int i = tid; i < 256 * 128; i += stride) {
      int n = i >> 7, k = i & 127;
      Wd1[i] = __float2bfloat16(dw1[k * 256 + n]);
    }
    for (int i = tid; i < 512 * 256; i += stride) {
      int n = i >> 8, k = i & 255;
      Wd2[i] = __float2bfloat16(dw2[k * 512 + n]);
    }
    for (int i = tid; i < 128 * 512; i += stride) {
      int n = i >> 9, k = i & 511;
      Wd3[i] = __float2bfloat16(n < 90 ? dw3[k * 90 + n] : 0.f);
    }
    return;
  }

  __shared__ __align__(16) char smem[SMEM_TOT];
  bf16* x1 = (bf16*)(smem + X_OFF);
  bf16* x2 = (bf16*)(smem + X_OFF);   // alias (x1 dead after L2 loop)
  bf16* x3 = (bf16*)(smem + X_OFF);   // alias (x2 dead after L3 loop)
  bf16* Bst = (bf16*)(smem + BST_OFF);
  float* sstat = (float*)(smem + SST_OFF);
  float* sstatF = (float*)(smem + SSF_OFF);

  const int lane = t & 63, wv = t >> 6;
  const int lrow = lane & 15, quad = lane >> 4;
  const bool rel = blockIdx.x < RELB;

  const bf16* W1 = rel ? Wt1 : Wj1;
  const bf16* W2 = rel ? Wt2 : Wj2;
  const bf16* W3 = rel ? Wt3 : Wj3;
  const float* B1 = rel ? b1 : jb1;
  const float* B2v = rel ? b2 : jb2;

  // stage W2 k-strip [256 cols][32] (source-side swizzle, 64B rows)
  auto stage2 = [&](int k0) {
#pragma unroll
    for (int c = 0; c < 4; ++c) {
      int cg = wv * 64 + c * 16;
      int col = cg + (lane >> 2);
      int ch = (lane & 3) ^ ((col >> 1) & 3);
      gload16(&W2[(size_t)col * 256 + k0 + ch * 8], &Bst[cg * 32]);
    }
  };
  // stage W3 strip s: [128 cols][64 k] (source-side swizzle, 128B rows)
  auto stage3 = [&](int s) {
#pragma unroll
    for (int c = 0; c < 4; ++c) {
      int cg = wv * 32 + c * 8;
      int row = cg + (lane >> 3);
      int ch = (lane & 7) ^ (row & 7);
      gload16(&W3[(size_t)row * 256 + s * 64 + ch * 8], &Bst[cg * 64]);
    }
  };

  stage2(0);  // issue first W2 strip; latency hides under x1 production

  // ---- produce whole x1 (64 rows x 256) upfront; A-frags direct from global ----
  short8 a0;       // rel: 32-wide input (26 valid)
  short8 aj[3];    // joint: 96-wide input
  if (rel) {
    const long gr = (long)blockIdx.x * 64 + wv * 16 + lrow;
    const float* ap = &rin[gr * 26];
    float v[8];
    if (quad < 3) {
#pragma unroll
      for (int u = 0; u < 4; ++u) {
        f32x2 f = *(const f32x2*)(ap + quad * 8 + u * 2);
        v[u * 2] = f[0];
        v[u * 2 + 1] = f[1];
      }
    } else {
      f32x2 f = *(const f32x2*)(ap + 24);
      v[0] = f[0];
      v[1] = f[1];
#pragma unroll
      for (int u = 2; u < 8; ++u) v[u] = 0.f;
    }
    bf16 pk[8];
#pragma unroll
    for (int u = 0; u < 8; ++u) pk[u] = __float2bfloat16(v[u]);
    a0 = *(short8*)pk;
  } else {
    const long gj = (long)(blockIdx.x - RELB) * 64 + wv * 16 + lrow;
#pragma unroll
    for (int ks = 0; ks < 3; ++ks) {
      const float* ap = &jin[gj * 96 + ks * 32 + quad * 8];
      f32x4 f0 = *(const f32x4*)ap;
      f32x4 f1 = *(const f32x4*)(ap + 4);
      bf16 pk[8];
#pragma unroll
      for (int u = 0; u < 4; ++u) {
        pk[u] = __float2bfloat16(f0[u]);
        pk[u + 4] = __float2bfloat16(f1[u]);
      }
      aj[ks] = *(short8*)pk;
    }
  }
#pragma unroll 2
  for (int ks8 = 0; ks8 < 8; ++ks8) {
#pragma unroll
    for (int ct = 0; ct < 2; ++ct) {
      f32x4 x = {0.f, 0.f, 0.f, 0.f};
      if (rel) {
        short8 bw = *(const short8*)&W1[(ks8 * 32 + ct * 16 + lrow) * 32 + quad * 8];
        x = __builtin_amdgcn_mfma_f32_16x16x32_bf16(bw, a0, x, 0, 0, 0);
      } else {
#pragma unroll
        for (int ks = 0; ks < 3; ++ks) {
          short8 bw =
              *(const short8*)&W1[(ks8 * 32 + ct * 16 + lrow) * 96 + ks * 32 + quad * 8];
          x = __builtin_amdgcn_mfma_f32_16x16x32_bf16(bw, aj[ks], x, 0, 0, 0);
        }
      }
      f32x4 bq = *(const f32x4*)&B1[ks8 * 32 + ct * 16 + quad * 4];
      bf16 pk[4];
#pragma unroll
      for (int r = 0; r < 4; ++r) pk[r] = __float2bfloat16(x[r] + bq[r]);
      *(s16x4*)&x1[(wv * 16 + lrow) * X2S + ks8 * 32 + ct * 16 + quad * 4] =
          *(s16x4*)pk;
    }
  }

  // ---- L2 (K=256): pure consume+stage loop ----
  f32x4 acc2[4][4];
#pragma unroll
  for (int i = 0; i < 4; ++i)
#pragma unroll
    for (int j = 0; j < 4; ++j) {
      f32x4 z = {0.f, 0.f, 0.f, 0.f};
      acc2[i][j] = z;
    }
  __syncthreads();  // x1 visible + Bst(0) drained
  for (int k = 0; k < 8; ++k) {
    short8 af[4], bfr[4];
#pragma unroll
    for (int i = 0; i < 4; ++i)
      af[i] = *(const short8*)&x1[(i * 16 + lrow) * X2S + k * 32 + quad * 8];
#pragma unroll
    for (int j = 0; j < 4; ++j) {
      int rb = wv * 64 + j * 16 + lrow;
      bfr[j] = *(const short8*)&Bst[rb * 32 + ((quad ^ ((rb >> 1) & 3)) * 8)];
    }
    // swapped: lane holds 4 consecutive x2 cols of one row
#pragma unroll
    for (int i = 0; i < 4; ++i)
#pragma unroll
      for (int j = 0; j < 4; ++j)
        acc2[i][j] =
            __builtin_amdgcn_mfma_f32_16x16x32_bf16(bfr[j], af[i], acc2[i][j], 0, 0, 0);
    __syncthreads();
    if (k < 7) {
      stage2((k + 1) * 32);
      __syncthreads();
    }
  }

  // write x2 from acc2 (aliases x1: all x1 reads done at loop's final barrier)
  {
#pragma unroll
    for (int i = 0; i < 4; ++i)
#pragma unroll
      for (int j = 0; j < 4; ++j) {
        f32x4 bq = *(const f32x4*)&B2v[wv * 64 + j * 16 + quad * 4];
        bf16 pk[4];
#pragma unroll
        for (int r = 0; r < 4; ++r) pk[r] = __float2bfloat16(acc2[i][j][r] + bq[r]);
        *(s16x4*)&x2[(i * 16 + lrow) * X2S + wv * 64 + j * 16 + quad * 4] =
            *(s16x4*)pk;
      }
    stage3(0);
  }
  __syncthreads();

  // ---- L3 (K=256, 128 cols): wave = 64 rows x 32 cols ----
  f32x4 acc3[4][2];
#pragma unroll
  for (int i = 0; i < 4; ++i) {
    f32x4 z = {0.f, 0.f, 0.f, 0.f};
    acc3[i][0] = z;
    acc3[i][1] = z;
  }
  for (int s = 0; s < 4; ++s) {
#pragma unroll
    for (int kk = 0; kk < 2; ++kk) {
      short8 af[4], bfr[2];
#pragma unroll
      for (int i = 0; i < 4; ++i)
        af[i] =
            *(const short8*)&x2[(i * 16 + lrow) * X2S + s * 64 + kk * 32 + quad * 8];
#pragma unroll
      for (int j = 0; j < 2; ++j) {
        int rb = wv * 32 + j * 16 + lrow;
        bfr[j] = *(const short8*)&Bst[rb * 64 + (((kk * 4 + quad) ^ (rb & 7)) * 8)];
      }
#pragma unroll
      for (int i = 0; i < 4; ++i)
#pragma unroll
        for (int j = 0; j < 2; ++j)
          acc3[i][j] =
              __builtin_amdgcn_mfma_f32_16x16x32_bf16(bfr[j], af[i], acc3[i][j], 0, 0, 0);
    }
    __syncthreads();
    if (s < 3) {
      stage3(s + 1);
      __syncthreads();
    }
  }

  if (!rel) {
    const long r0j = (long)(blockIdx.x - RELB) * 64;
#pragma unroll
    for (int i = 0; i < 4; ++i)
#pragma unroll
      for (int j = 0; j < 2; ++j) {
        f32x4 bq = *(const f32x4*)&jb3[wv * 32 + j * 16 + quad * 4];
        f32x4 out;
#pragma unroll
        for (int r = 0; r < 4; ++r) out[r] = acc3[i][j][r] + bq[r];
        *(f32x4*)&jf[(r0j + i * 16 + lrow) * 128 + wv * 32 + j * 16 + quad * 4] = out;
      }
    return;
  }

  // ---- rel: x3 write (alias x2, packed b64) + LN stats (2 shfl per i) ----
#pragma unroll
  for (int i = 0; i < 4; ++i) {
    float s1 = 0.f, s2 = 0.f;
#pragma unroll
    for (int j = 0; j < 2; ++j) {
      f32x4 bq = *(const f32x4*)&b3[wv * 32 + j * 16 + quad * 4];
      bf16 pk[4];
#pragma unroll
      for (int r = 0; r < 4; ++r) {
        float v = acc3[i][j][r] + bq[r];
        pk[r] = __float2bfloat16(v);
        s1 += v;
        s2 += v * v;
      }
      *(s16x4*)&x3[(i * 16 + lrow) * X3S + wv * 32 + j * 16 + quad * 4] = *(s16x4*)pk;
    }
    s1 += __shfl_xor(s1, 16, 64);
    s2 += __shfl_xor(s2, 16, 64);
    s1 += __shfl_xor(s1, 32, 64);
    s2 += __shfl_xor(s2, 32, 64);
    if (quad == 0) {
      int row = i * 16 + lrow;
      sstat[(row * 4 + wv) * 2] = s1;
      sstat[(row * 4 + wv) * 2 + 1] = s2;
    }
  }
  // hoist gemm32 A-operands (gWt, L1/L2-hot) across stats barriers
  short8 aw0[4], aw1[4];
#pragma unroll
  for (int kk = 0; kk < 4; ++kk) {
    aw0[kk] = *(const short8*)&gWt[lrow * 128 + kk * 32 + quad * 8];
    aw1[kk] = *(const short8*)&gWt[(16 + lrow) * 128 + kk * 32 + quad * 8];
  }
  __syncthreads();
  if (t < 64) {
    float s1 = 0.f, s2 = 0.f;
#pragma unroll
    for (int w = 0; w < 4; ++w) {
      s1 += sstat[(t * 4 + w) * 2];
      s2 += sstat[(t * 4 + w) * 2 + 1];
    }
    float mu = s1 * (1.f / 128.f);
    float var = s2 * (1.f / 128.f) - mu * mu;
    sstatF[t * 2] = mu;
    sstatF[t * 2 + 1] = rsqrtf(var + 1e-5f);
  }
  __syncthreads();

  // ---- gemm32: 32 out-chans x 64 rows (wave = 16 rows), LN stats trick, scatter ----
  {
    f32x4 ac0 = {0.f, 0.f, 0.f, 0.f}, ac1 = {0.f, 0.f, 0.f, 0.f};
#pragma unroll
    for (int kk = 0; kk < 4; ++kk) {
      short8 bbx = *(const short8*)&x3[(wv * 16 + lrow) * X3S + kk * 32 + quad * 8];
      ac0 = __builtin_amdgcn_mfma_f32_16x16x32_bf16(aw0[kk], bbx, ac0, 0, 0, 0);
      ac1 = __builtin_amdgcn_mfma_f32_16x16x32_bf16(aw1[kk], bbx, ac1, 0, 0, 0);
    }
    const long r0 = (long)blockIdx.x * 64;
    int drow = wv * 16 + lrow;
    long gr = r0 + drow;
    float mu = sstatF[drow * 2], inv = sstatF[drow * 2 + 1];
    int bb_ = (int)(gr >> 16);
    int nn = (int)((gr >> 8) & 255);
    int mm = (int)(gr & 255);
#pragma unroll
    for (int mt = 0; mt < 2; ++mt) {
      f32x4 a = mt ? ac1 : ac0;
#pragma unroll
      for (int reg = 0; reg < 4; ++reg) {
        int col = mt * 16 + quad * 4 + reg;
        float v = inv * (a[reg] - mu * sgW[col]) + bconst[col];
        int dd = col >> 3, hh = col & 7;
        attnR[((((long)dd * Bb + bb_) * Hh + hh) * Nn + nn) * Nn + mm] =
            __float2bfloat16(v);
      }
    }
  }
}

// =============== MFMA GEMM (generic, LDS-staged): decoder 2/3 ===============
template <typename TA, typename TC, bool GELU, bool RESID>
__global__ __launch_bounds__(256) void k_gemm_mfma(
    const TA* __restrict__ A, int Ka, int Kp, const bf16* __restrict__ Bt,
    const float* __restrict__ bias, TC* __restrict__ C, int ldc, int ncols,
    const float* __restrict__ resid) {
  __shared__ __align__(16) bf16 sA[128 * 32];
  __shared__ __align__(16) bf16 sB[128 * 32];
  const int t = threadIdx.x;
  const int lane = t & 63;
  const int wv = t >> 6;
  const int wr = wv >> 1, wc = wv & 1;
  const int lrow = lane & 15, quad = lane >> 4;
  const long row0 = (long)blockIdx.y * 128;
  const int n0 = blockIdx.x * 128;
  const int rg = lane >> 2;
  const int kE = (lane & 3) * 8;

  f32x4 zero = {0.f, 0.f, 0.f, 0.f};
  f32x4 acc[4][4];
#pragma unroll
  for (int i = 0; i < 4; ++i)
#pragma unroll
    for (int j = 0; j < 4; ++j) acc[i][j] = zero;

  for (int k0 = 0; k0 < Kp; k0 += 32) {
    {
      const int r0 = wv * 32;
      gload16(&Bt[(long)(n0 + r0 + rg) * Kp + k0 + kE], &sB[r0 * 32]);
      gload16(&Bt[(long)(n0 + r0 + 16 + rg) * Kp + k0 + kE], &sB[(r0 + 16) * 32]);
    }
    if (sizeof(TA) == 2) {
      const int r0 = wv * 32;
      gload16((const bf16*)&A[(row0 + r0 + rg) * (long)Ka + k0 + kE], &sA[r0 * 32]);
      gload16((const bf16*)&A[(row0 + r0 + 16 + rg) * (long)Ka + k0 + kE],
              &sA[(r0 + 16) * 32]);
    } else {
      for (int idx = t; idx < 128 * 32; idx += 256) {
        int r = idx >> 5, k = idx & 31;
        int gk = k0 + k;
        float v = (gk < Ka) ? toF(A[(row0 + r) * (long)Ka + gk]) : 0.f;
        sA[idx] = __float2bfloat16(v);
      }
    }
    __syncthreads();
    short8 af[4], bfr[4];
#pragma unroll
    for (int i = 0; i < 4; ++i)
      af[i] = *(const short8*)&sA[(wr * 64 + i * 16 + lrow) * 32 + quad * 8];
#pragma unroll
    for (int j = 0; j < 4; ++j)
      bfr[j] = *(const short8*)&sB[(wc * 64 + j * 16 + lrow) * 32 + quad * 8];
#pragma unroll
    for (int i = 0; i < 4; ++i)
#pragma unroll
      for (int j = 0; j < 4; ++j)
        acc[i][j] =
            __builtin_amdgcn_mfma_f32_16x16x32_bf16(af[i], bfr[j], acc[i][j], 0, 0, 0);
    __syncthreads();
  }

#pragma unroll
  for (int i = 0; i < 4; ++i) {
#pragma unroll
    for (int r = 0; r < 4; ++r) {
      int rl = wr * 64 + i * 16 + quad * 4 + r;
      long gr = row0 + rl;
#pragma unroll
      for (int j = 0; j < 4; ++j) {
        int gc = n0 + wc * 64 + j * 16 + lrow;
        if (gc < ncols) {
          float v = acc[i][j][r] + bias[gc];
          if (GELU) v = 0.5f * v * (1.f + erff(v * 0.70710678118654752f));
          if (RESID) v += resid[gr * (long)ldc + gc];
          stF(&C[gr * (long)ldc + gc], v);
        }
      }
    }
  }
}

// =============== k_lnqkv: row-LN (dim 128) fused into K=128 GEMM, 32-row blocks ===============
template <typename TC>
__global__ __launch_bounds__(256) void k_lnqkv(
    const float* __restrict__ A, const float* __restrict__ g,
    const float* __restrict__ b, const bf16* __restrict__ Bt,
    const float* __restrict__ bias, TC* __restrict__ C, int ldc, int ncols) {
  __shared__ __align__(16) bf16 sX[32 * XTS];
  const int t = threadIdx.x;
  const int lane = t & 63;
  const int wv = t >> 6;
  const int lrow = lane & 15, quad = lane >> 4;
  const long row0 = (long)blockIdx.y * 32;
  const int n0 = blockIdx.x * 128;

  {
    int row = t >> 3, prt = t & 7;
    const float* ap = &A[(row0 + row) * 128 + prt * 16];
    float v[16];
    float s1 = 0.f, s2 = 0.f;
#pragma unroll
    for (int u = 0; u < 4; ++u) {
      f32x4 q = *(const f32x4*)(ap + u * 4);
#pragma unroll
      for (int e = 0; e < 4; ++e) {
        v[u * 4 + e] = q[e];
        s1 += q[e];
        s2 += q[e] * q[e];
      }
    }
    s1 += __shfl_xor(s1, 1, 64);
    s2 += __shfl_xor(s2, 1, 64);
    s1 += __shfl_xor(s1, 2, 64);
    s2 += __shfl_xor(s2, 2, 64);
    s1 += __shfl_xor(s1, 4, 64);
    s2 += __shfl_xor(s2, 4, 64);
    float mu = s1 * (1.f / 128.f);
    float inv = rsqrtf(s2 * (1.f / 128.f) - mu * mu + 1e-5f);
#pragma unroll
    for (int u4 = 0; u4 < 4; ++u4) {
      bf16 pk[4];
#pragma unroll
      for (int e = 0; e < 4; ++e) {
        int c = prt * 16 + u4 * 4 + e;
        pk[e] = __float2bfloat16((v[u4 * 4 + e] - mu) * inv * g[c] + b[c]);
      }
      *(s16x4*)&sX[row * XTS + prt * 16 + u4 * 4] = *(s16x4*)pk;
    }
  }
  __syncthreads();

  f32x4 acc[2][2];
#pragma unroll
  for (int i = 0; i < 2; ++i)
#pragma unroll
    for (int j = 0; j < 2; ++j) {
      f32x4 z = {0.f, 0.f, 0.f, 0.f};
      acc[i][j] = z;
    }
#pragma unroll
  for (int k0 = 0; k0 < 128; k0 += 32) {
    short8 af[2], bfr[2];
#pragma unroll
    for (int j = 0; j < 2; ++j)
      bfr[j] = *(const short8*)&Bt[(long)(n0 + wv * 32 + j * 16 + lrow) * 128 + k0 +
                                   quad * 8];
#pragma unroll
    for (int i = 0; i < 2; ++i)
      af[i] = *(const short8*)&sX[(i * 16 + lrow) * XTS + k0 + quad * 8];
#pragma unroll
    for (int i = 0; i < 2; ++i)
#pragma unroll
      for (int j = 0; j < 2; ++j)
        acc[i][j] =
            __builtin_amdgcn_mfma_f32_16x16x32_bf16(af[i], bfr[j], acc[i][j], 0, 0, 0);
  }
#pragma unroll
  for (int i = 0; i < 2; ++i) {
#pragma unroll
    for (int r = 0; r < 4; ++r) {
      long gr = row0 + i * 16 + quad * 4 + r;
#pragma unroll
      for (int j = 0; j < 2; ++j) {
        int gc = n0 + wv * 32 + j * 16 + lrow;
        if (gc < ncols) stF(&C[gr * (long)ldc + gc], acc[i][j][r] + bias[gc]);
      }
    }
  }
}

// =============== k_tailq: proj+resid -> LN3 -> MLP(+gelu) -> resid [-> LN1' + QKV'] ===============
// 16-row blocks (grid 128) -- R7 evidence: non-rel3 portion -12us vs 32-row.
template <bool QKV>
__global__ __launch_bounds__(256) void k_tailq(
    const bf16* __restrict__ obuf, float* __restrict__ jf, const bf16* __restrict__ Wp,
    const float* __restrict__ pb, const float* __restrict__ g3,
    const float* __restrict__ b3, const bf16* __restrict__ Wm1,
    const float* __restrict__ m1b, const bf16* __restrict__ Wm2,
    const float* __restrict__ m2b, const float* __restrict__ g1n,
    const float* __restrict__ b1n, const bf16* __restrict__ Wqn,
    const float* __restrict__ qbn, float* __restrict__ qkvb) {
  __shared__ __align__(16) bf16 sX[16 * XTS];
  __shared__ __align__(16) bf16 sH[16 * XTS];
  __shared__ float sstat[16][4][2];
  __shared__ float sstatF[16][2];

  const int t = threadIdx.x;
  const int lane = t & 63;
  const int wv = t >> 6;
  const int lrow = lane & 15, quad = lane >> 4;
  const long row0 = (long)blockIdx.x * 16;

  {
    int r = t >> 4, c8 = (t & 15) * 8;
    *(uint4*)&sX[r * XTS + c8] = *(const uint4*)&obuf[(row0 + r) * 128 + c8];
  }
  __syncthreads();

  // ---- proj GEMM (16x128, K=128), wave n-split 32 ----
  f32x4 acc[2];
  {
    f32x4 z = {0.f, 0.f, 0.f, 0.f};
    acc[0] = z;
    acc[1] = z;
  }
#pragma unroll
  for (int k0 = 0; k0 < 128; k0 += 32) {
    short8 af = *(const short8*)&sX[lrow * XTS + k0 + quad * 8];
    short8 bfr[2];
#pragma unroll
    for (int j = 0; j < 2; ++j)
      bfr[j] = *(const short8*)&Wp[(wv * 32 + j * 16 + lrow) * 128 + k0 + quad * 8];
#pragma unroll
    for (int j = 0; j < 2; ++j)
      acc[j] = __builtin_amdgcn_mfma_f32_16x16x32_bf16(af, bfr[j], acc[j], 0, 0, 0);
  }
#pragma unroll
  for (int r = 0; r < 4; ++r) {
    int rl = quad * 4 + r;
    long gr = row0 + rl;
    float s1 = 0.f, s2 = 0.f;
#pragma unroll
    for (int j = 0; j < 2; ++j) {
      int gc = wv * 32 + j * 16 + lrow;
      float v = acc[j][r] + pb[gc] + jf[gr * 128 + gc];
      acc[j][r] = v;
      jf[gr * 128 + gc] = v;
      s1 += v;
      s2 += v * v;
    }
#pragma unroll
    for (int m = 1; m < 16; m <<= 1) {
      s1 += __shfl_xor(s1, m, 64);
      s2 += __shfl_xor(s2, m, 64);
    }
    if (lrow == 0) {
      sstat[rl][wv][0] = s1;
      sstat[rl][wv][1] = s2;
    }
  }
  __syncthreads();
  if (t < 16) {
    float s1 = 0.f, s2 = 0.f;
#pragma unroll
    for (int w = 0; w < 4; ++w) {
      s1 += sstat[t][w][0];
      s2 += sstat[t][w][1];
    }
    float mu = s1 * (1.f / 128.f);
    float var = s2 * (1.f / 128.f) - mu * mu;
    sstatF[t][0] = mu;
    sstatF[t][1] = rsqrtf(var + 1e-5f);
  }
  __syncthreads();
#pragma unroll
  for (int r = 0; r < 4; ++r) {
    int rl = quad * 4 + r;
    float mu = sstatF[rl][0], inv = sstatF[rl][1];
#pragma unroll
    for (int j = 0; j < 2; ++j) {
      int gc = wv * 32 + j * 16 + lrow;
      sX[rl * XTS + gc] = __float2bfloat16((acc[j][r] - mu) * inv * g3[gc] + b3[gc]);
    }
  }
  __syncthreads();

  // ---- MLP1 + gelu ----
  f32x4 acc2[2];
  {
    f32x4 z = {0.f, 0.f, 0.f, 0.f};
    acc2[0] = z;
    acc2[1] = z;
  }
#pragma unroll
  for (int k0 = 0; k0 < 128; k0 += 32) {
    short8 af = *(const short8*)&sX[lrow * XTS + k0 + quad * 8];
    short8 bfr[2];
#pragma unroll
    for (int j = 0; j < 2; ++j)
      bfr[j] = *(const short8*)&Wm1[(wv * 32 + j * 16 + lrow) * 128 + k0 + quad * 8];
#pragma unroll
    for (int j = 0; j < 2; ++j)
      acc2[j] = __builtin_amdgcn_mfma_f32_16x16x32_bf16(af, bfr[j], acc2[j], 0, 0, 0);
  }
#pragma unroll
  for (int r = 0; r < 4; ++r) {
    int rl = quad * 4 + r;
#pragma unroll
    for (int j = 0; j < 2; ++j) {
      int gc = wv * 32 + j * 16 + lrow;
      float v = acc2[j][r] + m1b[gc];
      v = 0.5f * v * (1.f + erff(v * 0.70710678118654752f));
      sH[rl * XTS + gc] = __float2bfloat16(v);
    }
  }
  __syncthreads();

  // ---- MLP2 + resid [+ stats] ----
  f32x4 acc3[2];
  {
    f32x4 z = {0.f, 0.f, 0.f, 0.f};
    acc3[0] = z;
    acc3[1] = z;
  }
#pragma unroll
  for (int k0 = 0; k0 < 128; k0 += 32) {
    short8 af = *(const short8*)&sH[lrow * XTS + k0 + quad * 8];
    short8 bfr[2];
#pragma unroll
    for (int j = 0; j < 2; ++j)
      bfr[j] = *(const short8*)&Wm2[(wv * 32 + j * 16 + lrow) * 128 + k0 + quad * 8];
#pragma unroll
    for (int j = 0; j < 2; ++j)
      acc3[j] = __builtin_amdgcn_mfma_f32_16x16x32_bf16(af, bfr[j], acc3[j], 0, 0, 0);
  }
#pragma unroll
  for (int r = 0; r < 4; ++r) {
    int rl = quad * 4 + r;
    long gr = row0 + rl;
    float s1 = 0.f, s2 = 0.f;
#pragma unroll
    for (int j = 0; j < 2; ++j) {
      int gc = wv * 32 + j * 16 + lrow;
      float v = acc3[j][r] + m2b[gc] + jf[gr * 128 + gc];
      acc3[j][r] = v;
      jf[gr * 128 + gc] = v;
      if (QKV) {
        s1 += v;
        s2 += v * v;
      }
    }
    if (QKV) {
#pragma unroll
      for (int m = 1; m < 16; m <<= 1) {
        s1 += __shfl_xor(s1, m, 64);
        s2 += __shfl_xor(s2, m, 64);
      }
      if (lrow == 0) {
        sstat[rl][wv][0] = s1;
        sstat[rl][wv][1] = s2;
      }
    }
  }
  if (!QKV) return;
  __syncthreads();
  if (t < 16) {
    float s1 = 0.f, s2 = 0.f;
#pragma unroll
    for (int w = 0; w < 4; ++w) {
      s1 += sstat[t][w][0];
      s2 += sstat[t][w][1];
    }
    float mu = s1 * (1.f / 128.f);
    float var = s2 * (1.f / 128.f) - mu * mu;
    sstatF[t][0] = mu;
    sstatF[t][1] = rsqrtf(var + 1e-5f);
  }
  __syncthreads();
#pragma unroll
  for (int r = 0; r < 4; ++r) {
    int rl = quad * 4 + r;
    float mu = sstatF[rl][0], inv = sstatF[rl][1];
#pragma unroll
    for (int j = 0; j < 2; ++j) {
      int gc = wv * 32 + j * 16 + lrow;
      sX[rl * XTS + gc] = __float2bfloat16((acc3[j][r] - mu) * inv * g1n[gc] + b1n[gc]);
    }
  }
  __syncthreads();
  for (int p = 0; p < 3; ++p) {
    f32x4 acc4[2];
    {
      f32x4 z = {0.f, 0.f, 0.f, 0.f};
      acc4[0] = z;
      acc4[1] = z;
    }
#pragma unroll
    for (int k0 = 0; k0 < 128; k0 += 32) {
      short8 af = *(const short8*)&sX[lrow * XTS + k0 + quad * 8];
      short8 bfr[2];
#pragma unroll
      for (int j = 0; j < 2; ++j)
        bfr[j] = *(const short8*)&Wqn[(long)(p * 128 + wv * 32 + j * 16 + lrow) * 128 +
                                      k0 + quad * 8];
#pragma unroll
      for (int j = 0; j < 2; ++j)
        acc4[j] = __builtin_amdgcn_mfma_f32_16x16x32_bf16(af, bfr[j], acc4[j], 0, 0, 0);
    }
#pragma unroll
    for (int r = 0; r < 4; ++r) {
      long gr = row0 + quad * 4 + r;
#pragma unroll
      for (int j = 0; j < 2; ++j) {
        int gc = p * 128 + wv * 32 + j * 16 + lrow;
        qkvb[gr * 384 + gc] = acc4[j][r] + qbn[gc];
      }
    }
  }
}

// ---- prep (EARLY ONLY): weights needed by k_rel3 itself; late prep rides k_rel3 ----
__global__ void k_prep(const float* re_w1, const float* re_w2, const float* re_w3,
                       const float* ln2_g, const float* ln2_b, const float* rconv_w,
                       const float* rconv_b, const float* je_w1, const float* je_w2,
                       const float* je_w3, bf16* Wt1, bf16* Wt2, bf16* Wt3, bf16* gWt,
                       float* sgW, float* bconst, bf16* Wj1, bf16* Wj2, bf16* Wj3) {
  const int stride = gridDim.x * blockDim.x;
  const int tid = blockIdx.x * blockDim.x + threadIdx.x;
  for (int i = tid; i < 256 * 32; i += stride) {
    int n = i >> 5, k = i & 31;
    Wt1[i] = __float2bfloat16(k < 26 ? re_w1[k * 256 + n] : 0.f);
  }
  for (int i = tid; i < 256 * 256; i += stride) {
    int n = i >> 8, k = i & 255;
    Wt2[i] = __float2bfloat16(re_w2[k * 256 + n]);
  }
  for (int i = tid; i < 128 * 256; i += stride) {
    int n = i >> 8, k = i & 255;
    Wt3[i] = __float2bfloat16(re_w3[k * 128 + n]);
  }
  for (int i = tid; i < 32 * 128; i += stride) {
    int col = i >> 7, c = i & 127;
    int dd = col >> 3, h = col & 7;
    gWt[i] = __float2bfloat16(ln2_g[dd * 128 + c] * rconv_w[(dd * 128 + c) * 8 + h]);
  }
  if (tid < 32) {
    int dd = tid >> 3, h = tid & 7;
    float sg = 0.f, bc = 0.f;
    for (int c = 0; c < 128; ++c) {
      float w = rconv_w[(dd * 128 + c) * 8 + h];
      sg += ln2_g[dd * 128 + c] * w;
      bc += ln2_b[dd * 128 + c] * w;
    }
    sgW[tid] = sg;
    bconst[tid] = bc + rconv_b[tid];
  }
  for (int i = tid; i < 256 * 96; i += stride) {
    int n = i / 96, k = i - n * 96;
    Wj1[i] = __float2bfloat16(je_w1[k * 256 + n]);
  }
  for (int i = tid; i < 256 * 256; i += stride) {
    int n = i >> 8, k = i & 255;
    Wj2[i] = __float2bfloat16(je_w2[k * 256 + n]);
  }
  for (int i = tid; i < 128 * 256; i += stride) {
    int n = i >> 8, k = i & 255;
    Wj3[i] = __float2bfloat16(je_w3[k * 128 + n]);
  }
}

// ---- fused attention: 4 independent waves per block, one wave per (b,h,n) ----
__global__ __launch_bounds__(256) void k_attn(const float* __restrict__ qkv,
                                              const bf16* __restrict__ aR,
                                              const float* __restrict__ conn,
                                              bf16* __restrict__ obuf) {
  __shared__ float p[4][4 * 68];
  const int wv = threadIdx.x >> 6;
  const int n = blockIdx.x * 4 + wv;
  const int h = blockIdx.y, b = blockIdx.z;
  const int lane = threadIdx.x & 63;
  const long rowq = (long)(b * Nn + n);
  const float* qp = &qkv[rowq * 384 + h * 16];
  f32x4 q0 = *(const f32x4*)qp;
  f32x4 q1 = *(const f32x4*)(qp + 4);
  f32x4 q2 = *(const f32x4*)(qp + 8);
  f32x4 q3 = *(const f32x4*)(qp + 12);
  const bf16* arp = &aR[((long)(b * Hh + h) * Nn + n) * Nn];
  const float* cnp = &conn[rowq * Nn];

  float lg[4];
#pragma unroll
  for (int s = 0; s < 4; ++s) {
    int m = s * 64 + lane;
    const float* kp = &qkv[((long)(b * Nn + m)) * 384 + 128 + h * 16];
    f32x4 k0 = *(const f32x4*)kp;
    f32x4 k1 = *(const f32x4*)(kp + 4);
    f32x4 k2 = *(const f32x4*)(kp + 8);
    f32x4 k3 = *(const f32x4*)(kp + 12);
    float d = 0.f;
#pragma unroll
    for (int e = 0; e < 4; ++e)
      d += q0[e] * k0[e] + q1[e] * k1[e] + q2[e] * k2[e] + q3[e] * k3[e];
    d += __bfloat162float(arp[m]);
    lg[s] = d * cnp[m] * 0.25f;
  }
  float mx = fmaxf(fmaxf(lg[0], lg[1]), fmaxf(lg[2], lg[3]));
#pragma unroll
  for (int off = 32; off; off >>= 1) mx = fmaxf(mx, __shfl_xor(mx, off, 64));
  float ex[4], ssum = 0.f;
#pragma unroll
  for (int s = 0; s < 4; ++s) {
    ex[s] = expf(lg[s] - mx);
    ssum += ex[s];
  }
#pragma unroll
  for (int off = 32; off; off >>= 1) ssum += __shfl_xor(ssum, off, 64);
#pragma unroll
  for (int s = 0; s < 4; ++s) p[wv][s * 68 + lane] = ex[s];
  float rinv = 1.f / ssum;

  const int c = lane & 15, sg = lane >> 4;
  const float* vp = &qkv[((long)(b * Nn + sg * 64)) * 384 + 256 + h * 16 + c];
  float acc = 0.f;
#pragma unroll
  for (int u = 0; u < 16; ++u) {
    f32x4 pq = *(const f32x4*)&p[wv][sg * 68 + u * 4];
#pragma unroll
    for (int e = 0; e < 4; ++e) acc += pq[e] * vp[(long)(u * 4 + e) * 384];
  }
  acc += __shfl_xor(acc, 16, 64);
  acc += __shfl_xor(acc, 32, 64);
  if (lane < 16) obuf[rowq * 128 + h * 16 + lane] = __float2bfloat16(acc * rinv);
}

extern "C" void kernel_launch(void* const* d_in, const int* in_sizes, int n_in,
                              void* d_out, int out_size, void* d_ws, size_t ws_size,
                              hipStream_t stream) {
  const float* joint_in = (const float*)d_in[0];
  const float* relation_in = (const float*)d_in[1];
  const float* conn = (const float*)d_in[2];
  const float* je_w1 = (const float*)d_in[3];
  const float* je_b1 = (const float*)d_in[4];
  const float* je_w2 = (const float*)d_in[5];
  const float* je_b2 = (const float*)d_in[6];
  const float* je_w3 = (const float*)d_in[7];
  const float* je_b3 = (const float*)d_in[8];
  const float* re_w1 = (const float*)d_in[9];
  const float* re_b1 = (const float*)d_in[10];
  const float* re_w2 = (const float*)d_in[11];
  const float* re_b2 = (const float*)d_in[12];
  const float* re_w3 = (const float*)d_in[13];
  const float* re_b3 = (const float*)d_in[14];
  const float* qkv_w = (const float*)d_in[15];
  const float* qkv_b = (const float*)d_in[16];
  const float* rconv_w = (const float*)d_in[17];
  const float* rconv_b = (const float*)d_in[18];
  const float* proj_w = (const float*)d_in[19];
  const float* proj_b = (const float*)d_in[20];
  const float* ln1_g = (const float*)d_in[21];
  const float* ln1_b = (const float*)d_in[22];
  const float* ln2_g = (const float*)d_in[23];
  const float* ln2_b = (const float*)d_in[24];
  const float* ln3_g = (const float*)d_in[25];
  const float* ln3_b = (const float*)d_in[26];
  const float* mw1 = (const float*)d_in[27];
  const float* mb1 = (const float*)d_in[28];
  const float* mw2 = (const float*)d_in[29];
  const float* mb2 = (const float*)d_in[30];
  const float* ng = (const float*)d_in[31];
  const float* nb = (const float*)d_in[32];
  const float* dw1 = (const float*)d_in[33];
  const float* db1 = (const float*)d_in[34];
  const float* dw2 = (const float*)d_in[35];
  const float* db2 = (const float*)d_in[36];
  const float* dw3 = (const float*)d_in[37];
  const float* db3 = (const float*)d_in[38];

  char* ws = (char*)d_ws;
  size_t off = 0;
  auto alloc = [&](size_t bytes) -> void* {
    void* p = ws + off;
    off += (bytes + 255) & ~(size_t)255;
    return p;
  };
  bf16* attnR = (bf16*)alloc((size_t)DEPTHd * Bb * Hh * Nn * Nn * 2);
  bf16* Wt1 = (bf16*)alloc(256 * 32 * 2);
  bf16* Wt2 = (bf16*)alloc(256 * 256 * 2);
  bf16* Wt3 = (bf16*)alloc(128 * 256 * 2);
  bf16* gWt = (bf16*)alloc(32 * 128 * 2);
  float* sgW = (float*)alloc(32 * 4);
  float* bconst = (float*)alloc(32 * 4);
  bf16* Wj1 = (bf16*)alloc(256 * 96 * 2);
  bf16* Wj2 = (bf16*)alloc(256 * 256 * 2);
  bf16* Wj3 = (bf16*)alloc(128 * 256 * 2);
  bf16* Wq = (bf16*)alloc(4 * 384 * 128 * 2);
  bf16* Wp = (bf16*)alloc(4 * 128 * 128 * 2);
  bf16* Wm1 = (bf16*)alloc(4 * 128 * 128 * 2);
  bf16* Wm2 = (bf16*)alloc(4 * 128 * 128 * 2);
  bf16* Wd1 = (bf16*)alloc(256 * 128 * 2);
  bf16* Wd2 = (bf16*)alloc(512 * 256 * 2);
  bf16* Wd3 = (bf16*)alloc(128 * 512 * 2);
  float* jf = (float*)alloc((size_t)BN * 128 * 4);
  bf16* obuf = (bf16*)alloc((size_t)BN * 128 * 2);
  char* U = (char*)alloc((size_t)BN * 384 * 4);
  float* qkvb = (float*)U;
  bf16* u1 = (bf16*)U;
  bf16* u2 = (bf16*)(U + (size_t)BN * 256 * 2);

  // early prep: only what k_rel3 consumes (Wt*, Wj*, gWt, sgW, bconst)
  k_prep<<<dim3(256), dim3(256), 0, stream>>>(
      re_w1, re_w2, re_w3, ln2_g, ln2_b, rconv_w, rconv_b, je_w1, je_w2, je_w3,
      Wt1, Wt2, Wt3, gWt, sgW, bconst, Wj1, Wj2, Wj3);

  // relation encoder (fills attnR) + joint encoder (fills jf) + late weight prep
  k_rel3<<<dim3(RELB + JB + PREPB), dim3(256), 0, stream>>>(
      relation_in, Wt1, re_b1, Wt2, re_b2, Wt3, re_b3, gWt, sgW, bconst, attnR,
      joint_in, Wj1, je_b1, Wj2, je_b2, Wj3, je_b3, jf,
      qkv_w, proj_w, mw1, mw2, dw1, dw2, dw3, Wq, Wp, Wm1, Wm2, Wd1, Wd2, Wd3);

  // depth 0 QKV
  k_lnqkv<float><<<dim3(3, 64), dim3(256), 0, stream>>>(
      jf, ln1_g, ln1_b, Wq, qkv_b, qkvb, 384, 384);

  for (int d = 0; d < DEPTHd; ++d) {
    k_attn<<<dim3(Nn / 4, Hh, Bb), dim3(256), 0, stream>>>(
        qkvb, attnR + (size_t)d * Bb * Hh * Nn * Nn, conn, obuf);
    if (d < 3) {
      k_tailq<true><<<dim3(128), dim3(256), 0, stream>>>(
          obuf, jf, Wp + (size_t)d * 16384, proj_b + d * 128, ln3_g + d * 128,
          ln3_b + d * 128, Wm1 + (size_t)d * 16384, mb1 + d * 128,
          Wm2 + (size_t)d * 16384, mb2 + d * 128, ln1_g + (d + 1) * 128,
          ln1_b + (d + 1) * 128, Wq + (size_t)(d + 1) * 49152, qkv_b + (d + 1) * 384,
          qkvb);
    } else {
      k_tailq<false><<<dim3(128), dim3(256), 0, stream>>>(
          obuf, jf, Wp + (size_t)d * 16384, proj_b + d * 128, ln3_g + d * 128,
          ln3_b + d * 128, Wm1 + (size_t)d * 16384, mb1 + d * 128,
          Wm2 + (size_t)d * 16384, mb2 + d * 128, nullptr, nullptr, nullptr, nullptr,
          nullptr);
    }
  }

  // final LN fused into decoder layer 1; then 256 -> 512 -> 90
  k_lnqkv<bf16><<<dim3(2, 64), dim3(256), 0, stream>>>(jf, ng, nb, Wd1, db1, u1, 256,
                                                       256);
  k_gemm_mfma<bf16, bf16, false, false><<<dim3(4, 16), dim3(256), 0, stream>>>(
      u1, 256, 256, Wd2, db2, u2, 512, 512, nullptr);
  k_gemm_mfma<bf16, float, false, false><<<dim3(1, 16), dim3(256), 0, stream>>>(
      u2, 512, 512, Wd3, db3, (float*)d_out, 90, 90, nullptr);
}